// Round 7
// baseline (291.304 us; speedup 1.0000x reference)
//
#include <hip/hip_runtime.h>
#include <hip/hip_bf16.h>
#include <math.h>

#define NTOT 8192
#define HB   4096
#define DIM  256
#define RANK_N (4096*19)
#define NORM_BLOCKS (NTOT/4)
#define RANK_BLOCKS (RANK_N/256)
#define ZERO_BLOCKS 2
#define INV_T 14.285714285714286f
#define SHIFT 16.0f
#define MAXP  48
#define POST_BLOCKS (NTOT/256)

typedef __attribute__((ext_vector_type(8))) short bf16x8_t;
typedef __attribute__((ext_vector_type(4))) float f32x4_t;

__device__ __forceinline__ unsigned short f2bf(float f) {
  union { float fv; unsigned int u; } v; v.fv = f;
  unsigned int u = v.u;
  unsigned int r = u + 0x7FFFu + ((u >> 16) & 1u);
  return (unsigned short)(r >> 16);
}

__device__ __forceinline__ const float* zrow(const float* za, const float* zb, int g) {
  return g < HB ? za + (size_t)g * DIM : zb + (size_t)(g - HB) * DIM;
}
__device__ __forceinline__ int piece_of(const int* pa, const int* pb, int g) {
  return g < HB ? pa[g] : pb[g - HB];
}

// ---- K1: normalize->bf16 | ranking BCE partials | zero ws buffers ----
__global__ void k_pre(const float* __restrict__ za, const float* __restrict__ zb,
                      const float* __restrict__ logits, const float* __restrict__ la,
                      const float* __restrict__ lb,
                      const int* __restrict__ pa, const int* __restrict__ pb,
                      unsigned short* __restrict__ zn, float* __restrict__ rank_part,
                      float* __restrict__ neg_s, int* __restrict__ posCount,
                      float* __restrict__ accf, int* __restrict__ done) {
  __shared__ float sred[8];
  int bid = blockIdx.x;
  int t = threadIdx.x;
  if (bid < NORM_BLOCKS) {
    int lane = t & 63, w = t >> 6;
    int row = bid * 4 + w;
    const float* src = zrow(za, zb, row);
    float4 v = *reinterpret_cast<const float4*>(src + lane * 4);
    float ss = v.x * v.x + v.y * v.y + v.z * v.z + v.w * v.w;
    for (int o = 32; o; o >>= 1) ss += __shfl_xor(ss, o, 64);
    float inv = 1.0f / fmaxf(sqrtf(ss), 1e-8f);
    ushort4 o;
    o.x = f2bf(v.x * inv); o.y = f2bf(v.y * inv);
    o.z = f2bf(v.z * inv); o.w = f2bf(v.w * inv);
    *reinterpret_cast<ushort4*>(zn + (size_t)row * DIM + lane * 4) = o;
  } else if (bid < NORM_BLOCKS + RANK_BLOCKS) {
    int rb = bid - NORM_BLOCKS;
    int e = rb * 256 + t;
    float lsum = 0.f, lcnt = 0.f;
    float diff = la[e] - lb[e];
    if (fabsf(diff) >= 0.05f) {
      float x = logits[e];
      float tgt = diff > 0.f ? 0.95f : 0.05f;
      lsum = fmaxf(x, 0.f) - x * tgt + log1pf(__expf(-fabsf(x)));
      lcnt = 1.f;
    }
    for (int o = 32; o; o >>= 1) { lsum += __shfl_xor(lsum, o, 64); lcnt += __shfl_xor(lcnt, o, 64); }
    int w = t >> 6, lane = t & 63;
    if (lane == 0) { sred[w * 2] = lsum; sred[w * 2 + 1] = lcnt; }
    __syncthreads();
    if (t == 0) {
      float S = 0.f, C = 0.f;
      for (int i = 0; i < 4; ++i) { S += sred[i * 2]; C += sred[i * 2 + 1]; }
      rank_part[rb * 2] = S;
      rank_part[rb * 2 + 1] = C;
    }
  } else {
    int z = bid - NORM_BLOCKS - RANK_BLOCKS;
    if (z == 0) {
      for (int k = t; k < NTOT; k += 256) neg_s[k] = 0.f;
      if (t == 0) { accf[0] = 0.f; accf[1] = 0.f; accf[2] = 0.f; accf[3] = 0.f; *done = 0; }
    } else {
      for (int k = t; k < NTOT; k += 256) posCount[k] = 0;
    }
  }
}

// ---- K2: Gram + neg-exp-sum + positive-sim capture ----
// Barrier-free, LDS-free: B fragments load straight from zn (4 MB, L2-resident).
// grid 1024: it = bid>>4 (128-row i-tile), chunk = bid&15 (512-col j-range)
__global__ __launch_bounds__(256, 3)
void k_gram(const unsigned short* __restrict__ zn,
            const int* __restrict__ pa, const int* __restrict__ pb,
            float* __restrict__ neg_s, int* __restrict__ posCount,
            float* __restrict__ pos_sims) {
  const int t = threadIdx.x;
  const int lane = t & 63;
  const int w = t >> 6;
  const int l15 = lane & 15;
  const int lg = lane >> 4;
  const int it = blockIdx.x >> 4;
  const int chunk = blockIdx.x & 15;
  const int ibase = it * 128;
  const int jbase0 = chunk * 512;

  // A fragments: 2 m-tiles x 8 k-steps (64 VGPRs), from normalized bf16
  bf16x8_t afrag[2][8];
#pragma unroll
  for (int mt = 0; mt < 2; ++mt) {
    int garow = ibase + w * 32 + mt * 16 + l15;
    const unsigned short* asrc = zn + (size_t)garow * DIM;
#pragma unroll
    for (int ks = 0; ks < 8; ++ks)
      afrag[mt][ks] = *reinterpret_cast<const bf16x8_t*>(asrc + lg * 8 + ks * 32);
  }

  int prow[8];
#pragma unroll
  for (int mt = 0; mt < 2; ++mt)
#pragma unroll
    for (int r = 0; r < 4; ++r)
      prow[mt * 4 + r] = piece_of(pa, pb, ibase + w * 32 + mt * 16 + lg * 4 + r);

  float s[8] = {0.f, 0.f, 0.f, 0.f, 0.f, 0.f, 0.f, 0.f};

  // 32 j-tiles of 16 cols; lane (l15, lg) reads row jr, k-bytes [lg*16 + ks*64).
  // Per wave-instruction: 16 rows x contiguous 64 B -> full 64B-line utilization.
  for (int m = 0; m < 32; ++m) {
    int jr = jbase0 + m * 16 + l15;
    int pc = piece_of(pa, pb, jr);
    const unsigned short* bsrc = zn + (size_t)jr * DIM + lg * 8;
    bf16x8_t bfrag[8];
#pragma unroll
    for (int ks = 0; ks < 8; ++ks)   // 8 independent dwordx4, imm-offset folded
      bfrag[ks] = *reinterpret_cast<const bf16x8_t*>(bsrc + ks * 32);
    f32x4_t acc0 = {0.f, 0.f, 0.f, 0.f};
    f32x4_t acc1 = {0.f, 0.f, 0.f, 0.f};
#pragma unroll
    for (int ks = 0; ks < 8; ++ks) {
      acc0 = __builtin_amdgcn_mfma_f32_16x16x32_bf16(afrag[0][ks], bfrag[ks], acc0, 0, 0, 0);
      acc1 = __builtin_amdgcn_mfma_f32_16x16x32_bf16(afrag[1][ks], bfrag[ks], acc1, 0, 0, 0);
    }
#pragma unroll
    for (int r = 0; r < 4; ++r) {
      int gi0 = ibase + w * 32 + lg * 4 + r;
      float sim0 = acc0[r] * INV_T;
      if (pc != prow[r]) {
        s[r] += __expf(sim0 - SHIFT);
      } else if (jr != gi0) {
        int slot = atomicAdd(&posCount[gi0], 1);
        if (slot < MAXP) pos_sims[(size_t)gi0 * MAXP + slot] = sim0;
      }
      int gi1 = gi0 + 16;
      float sim1 = acc1[r] * INV_T;
      if (pc != prow[4 + r]) {
        s[4 + r] += __expf(sim1 - SHIFT);
      } else if (jr != gi1) {
        int slot = atomicAdd(&posCount[gi1], 1);
        if (slot < MAXP) pos_sims[(size_t)gi1 * MAXP + slot] = sim1;
      }
    }
  }
  // reduce each row-sum across the 16 l15 lanes, then one atomic per row
#pragma unroll
  for (int q = 0; q < 8; ++q) {
    float v = s[q];
    v += __shfl_xor(v, 1, 64);
    v += __shfl_xor(v, 2, 64);
    v += __shfl_xor(v, 4, 64);
    v += __shfl_xor(v, 8, 64);
    if (l15 == 0)
      atomicAdd(&neg_s[ibase + w * 32 + (q >> 2) * 16 + lg * 4 + (q & 3)], v);
  }
}

// ---- K3: positive-pair terms + last-block finalize ----
__global__ void k_post(const float* __restrict__ neg_s,
                       const int* __restrict__ posCount, const float* __restrict__ pos_sims,
                       const float* __restrict__ rank_part,
                       float* __restrict__ accf, int* __restrict__ done,
                       float* __restrict__ out) {
  int t = threadIdx.x;
  int i = blockIdx.x * 256 + t;
  float lsum = 0.f, lcnt = 0.f;
  int posCnt = posCount[i];                    // exact count of same-piece j != i
  if (posCnt > 0 && posCnt < NTOT - 1) {       // valid anchor: >=1 pos and >=1 neg
    float nlse = SHIFT + logf(neg_s[i]);
    int m = posCnt < MAXP ? posCnt : MAXP;
    for (int s = 0; s < m; ++s) {
      float x = nlse - pos_sims[(size_t)i * MAXP + s];
      lsum += fmaxf(x, 0.f) + log1pf(__expf(-fabsf(x)));
    }
    lcnt = (float)posCnt;
  }
  for (int o = 32; o; o >>= 1) { lsum += __shfl_xor(lsum, o, 64); lcnt += __shfl_xor(lcnt, o, 64); }
  __shared__ float sred[8];
  __shared__ int isLast;
  int w = t >> 6, lane = t & 63;
  if (lane == 0) { sred[w * 2] = lsum; sred[w * 2 + 1] = lcnt; }
  __syncthreads();
  if (t == 0) {
    float S = 0.f, C = 0.f;
    for (int k = 0; k < 4; ++k) { S += sred[k * 2]; C += sred[k * 2 + 1]; }
    atomicAdd(&accf[2], S);
    atomicAdd(&accf[3], C);
    __threadfence();
    int old = atomicAdd(done, 1);
    isLast = (old == POST_BLOCKS - 1);
  }
  __syncthreads();
  if (isLast) {
    __threadfence();
    float rs = 0.f, rc = 0.f;
    for (int rb = t; rb < RANK_BLOCKS; rb += 256) {
      rs += rank_part[rb * 2];
      rc += rank_part[rb * 2 + 1];
    }
    for (int o = 32; o; o >>= 1) { rs += __shfl_xor(rs, o, 64); rc += __shfl_xor(rc, o, 64); }
    if (lane == 0) { sred[w * 2] = rs; sred[w * 2 + 1] = rc; }
    __syncthreads();
    if (t == 0) {
      float RS = 0.f, RC = 0.f;
      for (int k = 0; k < 4; ++k) { RS += sred[k * 2]; RC += sred[k * 2 + 1]; }
      float ps = accf[2], pcn = accf[3];
      float l_rank = RC > 0.f ? RS / RC : 0.f;
      float l_con = pcn > 0.f ? ps / pcn : 0.f;
      out[0] = l_rank + 0.3f * l_con;
      out[1] = l_rank;
      out[2] = l_con;
    }
  }
}

extern "C" void kernel_launch(void* const* d_in, const int* in_sizes, int n_in,
                              void* d_out, int out_size, void* d_ws, size_t ws_size,
                              hipStream_t stream) {
  const float* za     = (const float*)d_in[0];
  const float* zb     = (const float*)d_in[1];
  const float* logits = (const float*)d_in[2];
  const float* la     = (const float*)d_in[3];
  const float* lb     = (const float*)d_in[4];
  const int*   pa     = (const int*)d_in[5];
  const int*   pb     = (const int*)d_in[6];
  float* out = (float*)d_out;

  // ws layout (float words):
  //   [0..4)            accf (2,3 = pos_sum, pos_cnt)
  //   [4..8)            done (int) + pad
  //   [8..616)          rank_part[304][2]
  //   [616..8808)       neg_s[8192]
  //   [8808..17000)     posCount[8192] (int)
  //   [17000..410216)   pos_sims[8192*48]
  //   [410216.. )       zn[8192*256] bf16
  float* wsf = (float*)d_ws;
  int*   wsi = (int*)d_ws;
  float* accf      = wsf;
  int*   done      = wsi + 4;
  float* rank_part = wsf + 8;
  float* neg_s     = wsf + 616;
  int*   posCount  = wsi + 8808;
  float* pos_sims  = wsf + 17000;
  unsigned short* zn = (unsigned short*)(wsf + 410216);

  k_pre<<<NORM_BLOCKS + RANK_BLOCKS + ZERO_BLOCKS, 256, 0, stream>>>(
      za, zb, logits, la, lb, pa, pb, zn, rank_part, neg_s, posCount, accf, done);
  k_gram<<<1024, 256, 0, stream>>>(zn, pa, pb, neg_s, posCount, pos_sims);
  k_post<<<POST_BLOCKS, 256, 0, stream>>>(neg_s, posCount, pos_sims, rank_part, accf, done, out);
}

// Round 9
// 159.561 us; speedup vs baseline: 1.8257x; 1.8257x over previous
//
#include <hip/hip_runtime.h>
#include <hip/hip_bf16.h>
#include <math.h>

#define NTOT 8192
#define HB   4096
#define DIM  256
#define RANK_N (4096*19)
#define NORM_BLOCKS (NTOT/4)
#define RANK_BLOCKS (RANK_N/256)
#define ZERO_BLOCKS 2
#define INV_T 14.285714285714286f
#define SHIFT 16.0f
#define MAXP  48
#define POST_BLOCKS (NTOT/256)

typedef __attribute__((ext_vector_type(8))) short bf16x8_t;
typedef __attribute__((ext_vector_type(4))) float f32x4_t;

__device__ __forceinline__ unsigned short f2bf(float f) {
  union { float fv; unsigned int u; } v; v.fv = f;
  unsigned int u = v.u;
  unsigned int r = u + 0x7FFFu + ((u >> 16) & 1u);
  return (unsigned short)(r >> 16);
}

__device__ __forceinline__ const float* zrow(const float* za, const float* zb, int g) {
  return g < HB ? za + (size_t)g * DIM : zb + (size_t)(g - HB) * DIM;
}
__device__ __forceinline__ int piece_of(const int* pa, const int* pb, int g) {
  return g < HB ? pa[g] : pb[g - HB];
}

// async 16B global -> LDS (DMA, no VGPR round-trip). lds ptr must be wave-uniform.
__device__ __forceinline__ void gload_lds16(const unsigned short* g, unsigned short* l) {
  __builtin_amdgcn_global_load_lds(
      (const __attribute__((address_space(1))) unsigned int*)g,
      (__attribute__((address_space(3))) unsigned int*)l, 16, 0, 0);
}

// ---- K1: normalize->bf16 (chunk-XOR swizzled) | ranking BCE partials | zero ws ----
// zn layout: row r, logical 16B-chunk c stored at physical chunk (c ^ (r&7)).
__global__ void k_pre(const float* __restrict__ za, const float* __restrict__ zb,
                      const float* __restrict__ logits, const float* __restrict__ la,
                      const float* __restrict__ lb,
                      const int* __restrict__ pa, const int* __restrict__ pb,
                      unsigned short* __restrict__ zn, float* __restrict__ rank_part,
                      float* __restrict__ neg_s, int* __restrict__ posCount,
                      float* __restrict__ accf, int* __restrict__ done) {
  __shared__ float sred[8];
  int bid = blockIdx.x;
  int t = threadIdx.x;
  if (bid < NORM_BLOCKS) {
    int lane = t & 63, w = t >> 6;
    int row = bid * 4 + w;
    const float* src = zrow(za, zb, row);
    float4 v = *reinterpret_cast<const float4*>(src + lane * 4);
    float ss = v.x * v.x + v.y * v.y + v.z * v.z + v.w * v.w;
    for (int o = 32; o; o >>= 1) ss += __shfl_xor(ss, o, 64);
    float inv = 1.0f / fmaxf(sqrtf(ss), 1e-8f);
    ushort4 o;
    o.x = f2bf(v.x * inv); o.y = f2bf(v.y * inv);
    o.z = f2bf(v.z * inv); o.w = f2bf(v.w * inv);
    // lane covers logical ushorts [lane*4, lane*4+4): chunk = lane>>1, half = lane&1
    int phys = (((lane >> 1) ^ (row & 7)) << 3) + ((lane & 1) << 2);
    *reinterpret_cast<ushort4*>(zn + (size_t)row * DIM + phys) = o;
  } else if (bid < NORM_BLOCKS + RANK_BLOCKS) {
    int rb = bid - NORM_BLOCKS;
    int e = rb * 256 + t;
    float lsum = 0.f, lcnt = 0.f;
    float diff = la[e] - lb[e];
    if (fabsf(diff) >= 0.05f) {
      float x = logits[e];
      float tgt = diff > 0.f ? 0.95f : 0.05f;
      lsum = fmaxf(x, 0.f) - x * tgt + log1pf(__expf(-fabsf(x)));
      lcnt = 1.f;
    }
    for (int o = 32; o; o >>= 1) { lsum += __shfl_xor(lsum, o, 64); lcnt += __shfl_xor(lcnt, o, 64); }
    int w = t >> 6, lane = t & 63;
    if (lane == 0) { sred[w * 2] = lsum; sred[w * 2 + 1] = lcnt; }
    __syncthreads();
    if (t == 0) {
      float S = 0.f, C = 0.f;
      for (int i = 0; i < 4; ++i) { S += sred[i * 2]; C += sred[i * 2 + 1]; }
      rank_part[rb * 2] = S;
      rank_part[rb * 2 + 1] = C;
    }
  } else {
    int z = bid - NORM_BLOCKS - RANK_BLOCKS;
    if (z == 0) {
      for (int k = t; k < NTOT; k += 256) neg_s[k] = 0.f;
      if (t == 0) { accf[0] = 0.f; accf[1] = 0.f; accf[2] = 0.f; accf[3] = 0.f; *done = 0; }
    } else {
      for (int k = t; k < NTOT; k += 256) posCount[k] = 0;
    }
  }
}

// ---- K2: Gram + neg-exp-sum + positive-sim capture ----
// 2-phase global_load_lds pipeline, double-buffered LDS, swizzle-decoded reads.
// grid 1024: it = bid>>4 (128-row i-tile), chunk = bid&15 (512-col j-range)
__global__ __launch_bounds__(256, 2)
void k_gram(const unsigned short* __restrict__ zn,
            const int* __restrict__ pa, const int* __restrict__ pb,
            float* __restrict__ neg_s, int* __restrict__ posCount,
            float* __restrict__ pos_sims) {
  __shared__ unsigned short Bs[2][64 * 256];  // 2 x 32KB, linear (source pre-swizzled)
  __shared__ int Ps[512];
  const int t = threadIdx.x;
  const int lane = t & 63;
  const int w = t >> 6;
  const int l15 = lane & 15;
  const int lg = lane >> 4;
  const int it = blockIdx.x >> 4;
  const int chunk = blockIdx.x & 15;
  const int ibase = it * 128;
  const int jbase0 = chunk * 512;

  Ps[t]       = piece_of(pa, pb, jbase0 + t);
  Ps[t + 256] = piece_of(pa, pb, jbase0 + t + 256);

  // A fragments: 2 m-tiles x 8 k-steps; decode chunk swizzle (full 16B chunks)
  bf16x8_t afrag[2][8];
#pragma unroll
  for (int mt = 0; mt < 2; ++mt) {
    int garow = ibase + w * 32 + mt * 16 + l15;
    const unsigned short* asrc = zn + (size_t)garow * DIM;
    int sw = garow & 7;
#pragma unroll
    for (int ks = 0; ks < 8; ++ks)
      afrag[mt][ks] = *reinterpret_cast<const bf16x8_t*>(asrc + (((lg + ks * 4) ^ sw) << 3));
  }

  int prow[8];
#pragma unroll
  for (int mt = 0; mt < 2; ++mt)
#pragma unroll
    for (int r = 0; r < 4; ++r)
      prow[mt * 4 + r] = piece_of(pa, pb, ibase + w * 32 + mt * 16 + lg * 4 + r);

  float s[8] = {0.f, 0.f, 0.f, 0.f, 0.f, 0.f, 0.f, 0.f};

  // staging: wave w covers tile rows [w*16, w*16+16); 8 issues x 1KB (2 rows each).
  // lane l: global row = jb + w*16 + 2i + (l>>5), physical chunk (l&31) -> linear copy.
  const int srow = w * 16 + (lane >> 5);
  const int scol = (lane & 31) * 8;

#define STAGE(buf, jt_)                                                        \
  {                                                                            \
    int jb_ = jbase0 + (jt_) * 64;                                             \
    const unsigned short* g0 = zn + (size_t)(jb_ + srow) * DIM + scol;         \
    unsigned short* l0 = &Bs[buf][w * 4096];                                   \
    _Pragma("unroll")                                                          \
    for (int i_ = 0; i_ < 8; ++i_)                                             \
      gload_lds16(g0 + (size_t)(2 * i_) * DIM, l0 + i_ * 512);                 \
  }

  STAGE(0, 0)
  __syncthreads();  // drains vmcnt -> tile 0 resident

  int cur = 0;
  for (int jt = 0; jt < 8; ++jt) {
    if (jt < 7) STAGE(cur ^ 1, jt + 1)   // async; completes under compute
    const unsigned short* Bb = &Bs[cur][0];
#pragma unroll
    for (int ct = 0; ct < 4; ++ct) {
      int jl = jt * 64 + ct * 16 + l15;
      int pc = Ps[jl];
      int jj = jbase0 + jl;
      int brow = ct * 16 + l15;
      int bsw = brow & 7;
      const unsigned short* bbase = Bb + brow * 256;
      f32x4_t acc0 = {0.f, 0.f, 0.f, 0.f};
      f32x4_t acc1 = {0.f, 0.f, 0.f, 0.f};
#pragma unroll
      for (int ks = 0; ks < 8; ++ks) {
        bf16x8_t bfrag = *reinterpret_cast<const bf16x8_t*>(bbase + (((lg + ks * 4) ^ bsw) << 3));
        acc0 = __builtin_amdgcn_mfma_f32_16x16x32_bf16(afrag[0][ks], bfrag, acc0, 0, 0, 0);
        acc1 = __builtin_amdgcn_mfma_f32_16x16x32_bf16(afrag[1][ks], bfrag, acc1, 0, 0, 0);
      }
#pragma unroll
      for (int r = 0; r < 4; ++r) {
        int gi0 = ibase + w * 32 + lg * 4 + r;
        float sim0 = acc0[r] * INV_T;
        if (pc != prow[r]) {
          s[r] += __expf(sim0 - SHIFT);
        } else if (jj != gi0) {
          int slot = atomicAdd(&posCount[gi0], 1);
          if (slot < MAXP) pos_sims[(size_t)gi0 * MAXP + slot] = sim0;
        }
        int gi1 = gi0 + 16;
        float sim1 = acc1[r] * INV_T;
        if (pc != prow[4 + r]) {
          s[4 + r] += __expf(sim1 - SHIFT);
        } else if (jj != gi1) {
          int slot = atomicAdd(&posCount[gi1], 1);
          if (slot < MAXP) pos_sims[(size_t)gi1 * MAXP + slot] = sim1;
        }
      }
    }
    __syncthreads();  // drains next tile's loads; all readers of cur done
    cur ^= 1;
  }
#pragma unroll
  for (int q = 0; q < 8; ++q) {
    float v = s[q];
    v += __shfl_xor(v, 1, 64);
    v += __shfl_xor(v, 2, 64);
    v += __shfl_xor(v, 4, 64);
    v += __shfl_xor(v, 8, 64);
    if (l15 == 0)
      atomicAdd(&neg_s[ibase + w * 32 + (q >> 2) * 16 + lg * 4 + (q & 3)], v);
  }
#undef STAGE
}

// ---- K3: positive-pair terms + last-block finalize ----
__global__ void k_post(const float* __restrict__ neg_s,
                       const int* __restrict__ posCount, const float* __restrict__ pos_sims,
                       const float* __restrict__ rank_part,
                       float* __restrict__ accf, int* __restrict__ done,
                       float* __restrict__ out) {
  int t = threadIdx.x;
  int i = blockIdx.x * 256 + t;
  float lsum = 0.f, lcnt = 0.f;
  int posCnt = posCount[i];
  if (posCnt > 0 && posCnt < NTOT - 1) {
    float nlse = SHIFT + logf(neg_s[i]);
    int m = posCnt < MAXP ? posCnt : MAXP;
    for (int s = 0; s < m; ++s) {
      float x = nlse - pos_sims[(size_t)i * MAXP + s];
      lsum += fmaxf(x, 0.f) + log1pf(__expf(-fabsf(x)));
    }
    lcnt = (float)posCnt;
  }
  for (int o = 32; o; o >>= 1) { lsum += __shfl_xor(lsum, o, 64); lcnt += __shfl_xor(lcnt, o, 64); }
  __shared__ float sred[8];
  __shared__ int isLast;
  int w = t >> 6, lane = t & 63;
  if (lane == 0) { sred[w * 2] = lsum; sred[w * 2 + 1] = lcnt; }
  __syncthreads();
  if (t == 0) {
    float S = 0.f, C = 0.f;
    for (int k = 0; k < 4; ++k) { S += sred[k * 2]; C += sred[k * 2 + 1]; }
    atomicAdd(&accf[2], S);
    atomicAdd(&accf[3], C);
    __threadfence();
    int old = atomicAdd(done, 1);
    isLast = (old == POST_BLOCKS - 1);
  }
  __syncthreads();
  if (isLast) {
    __threadfence();
    float rs = 0.f, rc = 0.f;
    for (int rb = t; rb < RANK_BLOCKS; rb += 256) {
      rs += rank_part[rb * 2];
      rc += rank_part[rb * 2 + 1];
    }
    for (int o = 32; o; o >>= 1) { rs += __shfl_xor(rs, o, 64); rc += __shfl_xor(rc, o, 64); }
    if (lane == 0) { sred[w * 2] = rs; sred[w * 2 + 1] = rc; }
    __syncthreads();
    if (t == 0) {
      float RS = 0.f, RC = 0.f;
      for (int k = 0; k < 4; ++k) { RS += sred[k * 2]; RC += sred[k * 2 + 1]; }
      float ps = accf[2], pcn = accf[3];
      float l_rank = RC > 0.f ? RS / RC : 0.f;
      float l_con = pcn > 0.f ? ps / pcn : 0.f;
      out[0] = l_rank + 0.3f * l_con;
      out[1] = l_rank;
      out[2] = l_con;
    }
  }
}

extern "C" void kernel_launch(void* const* d_in, const int* in_sizes, int n_in,
                              void* d_out, int out_size, void* d_ws, size_t ws_size,
                              hipStream_t stream) {
  const float* za     = (const float*)d_in[0];
  const float* zb     = (const float*)d_in[1];
  const float* logits = (const float*)d_in[2];
  const float* la     = (const float*)d_in[3];
  const float* lb     = (const float*)d_in[4];
  const int*   pa     = (const int*)d_in[5];
  const int*   pb     = (const int*)d_in[6];
  float* out = (float*)d_out;

  float* wsf = (float*)d_ws;
  int*   wsi = (int*)d_ws;
  float* accf      = wsf;
  int*   done      = wsi + 4;
  float* rank_part = wsf + 8;
  float* neg_s     = wsf + 616;
  int*   posCount  = wsi + 8808;
  float* pos_sims  = wsf + 17000;
  unsigned short* zn = (unsigned short*)(wsf + 410216);

  k_pre<<<NORM_BLOCKS + RANK_BLOCKS + ZERO_BLOCKS, 256, 0, stream>>>(
      za, zb, logits, la, lb, pa, pb, zn, rank_part, neg_s, posCount, accf, done);
  k_gram<<<1024, 256, 0, stream>>>(zn, pa, pb, neg_s, posCount, pos_sims);
  k_post<<<POST_BLOCKS, 256, 0, stream>>>(neg_s, posCount, pos_sims, rank_part, accf, done, out);
}